// Round 1
// baseline (6760.012 us; speedup 1.0000x reference)
//
#include <hip/hip_runtime.h>
#include <hip/hip_bf16.h>
#include <math.h>

#define SEQ    1024
#define EMB    512
#define HID    512
#define G4     2048   // 4*HID
#define NBLK   32     // persistent scan blocks
#define UPB    16     // hidden units per scan block

// ---------------------------------------------------------------------------
// Phase A: x_gates[t][r] = dot(emb[tok[t]], w_ih[r]) + b_ih[r] + b_hh[r]
// 64x64 tile, K-chunks of 64, 4x4 micro-tile per thread.
// ---------------------------------------------------------------------------
__global__ __launch_bounds__(256) void xgates_kernel(
    const int* __restrict__ tok, const float* __restrict__ emb,
    const float* __restrict__ w_ih, const float* __restrict__ b_ih,
    const float* __restrict__ b_hh, float* __restrict__ xg)
{
  __shared__ float xs[64][68];   // +4 pad breaks power-of-2 bank stride
  __shared__ float wsh[64][68];
  __shared__ int   tok_s[64];

  const int tid = threadIdx.x;
  const int r0  = (int)blockIdx.x * 64;   // gate-row tile
  const int t0  = (int)blockIdx.y * 64;   // seq tile

  if (tid < 64) tok_s[tid] = tok[t0 + tid];
  __syncthreads();

  const int tx = tid & 15;   // r micro
  const int ty = tid >> 4;   // t micro

  float acc[4][4];
#pragma unroll
  for (int i = 0; i < 4; ++i)
#pragma unroll
    for (int j = 0; j < 4; ++j) acc[i][j] = 0.f;

  for (int kc = 0; kc < EMB; kc += 64) {
#pragma unroll
    for (int it = 0; it < 4; ++it) {
      int id  = it * 256 + tid;    // 0..1023 float4 slots
      int row = id >> 4;           // 0..63
      int c4  = id & 15;           // 0..15
      float4 xv = *(const float4*)(emb + (size_t)tok_s[row] * EMB + kc + c4 * 4);
      *(float4*)&xs[row][c4 * 4] = xv;
      float4 wv = *(const float4*)(w_ih + (size_t)(r0 + row) * EMB + kc + c4 * 4);
      *(float4*)&wsh[row][c4 * 4] = wv;
    }
    __syncthreads();

#pragma unroll
    for (int k4 = 0; k4 < 16; ++k4) {
      float4 xv[4], wv[4];
#pragma unroll
      for (int i = 0; i < 4; ++i) xv[i] = *(const float4*)&xs[ty * 4 + i][k4 * 4];
#pragma unroll
      for (int j = 0; j < 4; ++j) wv[j] = *(const float4*)&wsh[tx * 4 + j][k4 * 4];
#pragma unroll
      for (int i = 0; i < 4; ++i)
#pragma unroll
        for (int j = 0; j < 4; ++j) {
          acc[i][j] += xv[i].x * wv[j].x + xv[i].y * wv[j].y
                     + xv[i].z * wv[j].z + xv[i].w * wv[j].w;
        }
    }
    __syncthreads();
  }

  // epilogue: + (b_ih + b_hh)
  const int rbase = r0 + tx * 4;
  float bias[4];
#pragma unroll
  for (int j = 0; j < 4; ++j) bias[j] = b_ih[rbase + j] + b_hh[rbase + j];

#pragma unroll
  for (int i = 0; i < 4; ++i) {
    int t = t0 + ty * 4 + i;
    float4 o;
    o.x = acc[i][0] + bias[0];
    o.y = acc[i][1] + bias[1];
    o.z = acc[i][2] + bias[2];
    o.w = acc[i][3] + bias[3];
    *(float4*)(xg + (size_t)t * G4 + rbase) = o;
  }
}

// ---------------------------------------------------------------------------
// Phase B: sequential LSTM scan. 32 persistent blocks x 512 threads.
// Block b owns hidden units [16b,16b+16) -> 64 gate rows of w_hh in VGPRs
// (8 threads per row, 64 weights each). h broadcast via global double buffer
// + per-block monotonic flags (agent-scope atomics; XCD-coherence safe).
// ---------------------------------------------------------------------------
__global__ __launch_bounds__(512) void lstm_scan_kernel(
    const float* __restrict__ xg, const float* __restrict__ w_hh,
    float* h_buf /* [2][HID] */, unsigned int* flags /* [NBLK] */)
{
  __shared__ float h_lds[8 * 68];   // 512 h values, +4 pad per 64 (bank spread)
  __shared__ float gate_lds[64];

  const int tid = threadIdx.x;
  const int blk = blockIdx.x;
  const int g   = tid >> 3;          // 0..63: local gate row
  const int s   = tid & 7;           // 0..7 : k-segment (64 wide)
  const int q   = g >> 4;            // gate type 0..3 (i,f,g,o)
  const int jj  = g & 15;            // local hidden unit
  const int grow = q * HID + blk * UPB + jj;   // global gate row

  // Load this thread's 64 w_hh weights into registers.
  float wreg[64];
  {
    const float* wp = w_hh + (size_t)grow * HID + s * 64;
#pragma unroll
    for (int k4 = 0; k4 < 16; ++k4) {
      float4 v = ((const float4*)wp)[k4];
      wreg[k4 * 4 + 0] = v.x; wreg[k4 * 4 + 1] = v.y;
      wreg[k4 * 4 + 2] = v.z; wreg[k4 * 4 + 3] = v.w;
    }
  }

  float c_reg = 0.f;                  // cell state, block-local (tid<16 only)
  float xgv = (s == 0) ? xg[grow] : 0.f;   // x_gates[0][grow]

  for (int t = 0; t < SEQ; ++t) {
    // Prefetch next step's xg (independent of h -> overlaps barrier wait).
    float xgn = 0.f;
    if (s == 0) {
      int tn = (t + 1 < SEQ) ? (t + 1) : (SEQ - 1);
      xgn = xg[(size_t)tn * G4 + grow];
    }

    // Wait until every block has published h^t.
    if (t > 0) {
      if (tid < NBLK) {
        while (__hip_atomic_load(&flags[tid], __ATOMIC_ACQUIRE,
                                 __HIP_MEMORY_SCOPE_AGENT) < (unsigned)t) { }
      }
    }
    __syncthreads();

    // Stage h^t into LDS (padded layout: +4 floats per 64).
    const float* hsrc = h_buf + (t & 1) * HID;
    float hv = __hip_atomic_load(&hsrc[tid], __ATOMIC_RELAXED,
                                 __HIP_MEMORY_SCOPE_AGENT);
    h_lds[tid + (tid >> 6) * 4] = hv;
    __syncthreads();

    // 64-wide partial dot, 4 accumulators to break the FMA chain.
    const int base = s * 68;
    float p0 = 0.f, p1 = 0.f, p2 = 0.f, p3 = 0.f;
#pragma unroll
    for (int k = 0; k < 16; ++k) {
      p0 += wreg[k]      * h_lds[base + k];
      p1 += wreg[k + 16] * h_lds[base + 16 + k];
      p2 += wreg[k + 32] * h_lds[base + 32 + k];
      p3 += wreg[k + 48] * h_lds[base + 48 + k];
    }
    float p = (p0 + p1) + (p2 + p3);
    p += __shfl_xor(p, 1, 64);
    p += __shfl_xor(p, 2, 64);
    p += __shfl_xor(p, 4, 64);
    if (s == 0) gate_lds[g] = p + xgv;
    xgv = xgn;
    __syncthreads();

    // Gate math + publish h chunk (16 threads).
    if (tid < UPB) {
      float gi = gate_lds[tid];
      float gf = gate_lds[16 + tid];
      float gg = gate_lds[32 + tid];
      float go = gate_lds[48 + tid];
      float i_ = 1.f / (1.f + __expf(-gi));
      float f_ = 1.f / (1.f + __expf(-gf));
      float g_ = tanhf(gg);
      float o_ = 1.f / (1.f + __expf(-go));
      c_reg = f_ * c_reg + i_ * g_;
      float hval = o_ * tanhf(c_reg);
      float* hdst = h_buf + ((t + 1) & 1) * HID;
      __hip_atomic_store(&hdst[blk * UPB + tid], hval, __ATOMIC_RELEASE,
                         __HIP_MEMORY_SCOPE_AGENT);
    }
    __threadfence();
    __syncthreads();
    if (tid == 0) {
      __hip_atomic_store(&flags[blk], (unsigned)(t + 1), __ATOMIC_RELEASE,
                         __HIP_MEMORY_SCOPE_AGENT);
    }
  }
}

// ---------------------------------------------------------------------------
// Phase C: attn = sigmoid(h @ attn_w^T + attn_b) broadcast to (64,32,32);
// also emit x_instr_rep = h.
// ---------------------------------------------------------------------------
__global__ __launch_bounds__(256) void head_kernel(
    const float* __restrict__ h, const float* __restrict__ attn_w,
    const float* __restrict__ attn_b, float* __restrict__ out)
{
  __shared__ float red[4];
  __shared__ float aval;
  const int r   = blockIdx.x;   // 0..63
  const int tid = threadIdx.x;

  float p = attn_w[(size_t)r * HID + tid] * h[tid]
          + attn_w[(size_t)r * HID + 256 + tid] * h[256 + tid];
#pragma unroll
  for (int off = 1; off < 64; off <<= 1) p += __shfl_xor(p, off, 64);
  if ((tid & 63) == 0) red[tid >> 6] = p;
  __syncthreads();
  if (tid == 0) {
    float sum = red[0] + red[1] + red[2] + red[3] + attn_b[r];
    aval = 1.f / (1.f + __expf(-sum));
  }
  __syncthreads();

  float a = aval;
  float4 av = make_float4(a, a, a, a);
  ((float4*)(out + (size_t)r * 1024))[tid] = av;   // 256*16B = 1024 floats

  if (r == 0) {   // x_instr_rep = h (512 floats) at offset 64*32*32
    out[65536 + tid]       = h[tid];
    out[65536 + 256 + tid] = h[256 + tid];
  }
}

// ---------------------------------------------------------------------------
extern "C" void kernel_launch(void* const* d_in, const int* in_sizes, int n_in,
                              void* d_out, int out_size, void* d_ws, size_t ws_size,
                              hipStream_t stream) {
  const int*   tok    = (const int*)  d_in[0];
  const float* emb    = (const float*)d_in[1];
  const float* w_ih   = (const float*)d_in[2];
  const float* w_hh   = (const float*)d_in[3];
  const float* b_ih   = (const float*)d_in[4];
  const float* b_hh   = (const float*)d_in[5];
  const float* attn_w = (const float*)d_in[6];
  const float* attn_b = (const float*)d_in[7];
  float* out = (float*)d_out;

  char* ws = (char*)d_ws;
  float*        xg    = (float*)ws;                                   // 8 MB
  float*        h_buf = (float*)(ws + (size_t)SEQ * G4 * 4);          // 2*512 f
  unsigned int* flags = (unsigned int*)(ws + (size_t)SEQ * G4 * 4 + 4096);

  // ws is poisoned 0xAA before every launch: zero h^0 and the flags.
  hipMemsetAsync(h_buf, 0, 4096 + NBLK * sizeof(unsigned int), stream);

  dim3 gA(G4 / 64, SEQ / 64);   // 32 x 16 tiles
  xgates_kernel<<<gA, 256, 0, stream>>>(tok, emb, w_ih, b_ih, b_hh, xg);
  lstm_scan_kernel<<<NBLK, 512, 0, stream>>>(xg, w_hh, h_buf, flags);
  head_kernel<<<64, 256, 0, stream>>>(h_buf /* buf0 = h^1024 */, attn_w, attn_b, out);
}

// Round 2
// 1764.867 us; speedup vs baseline: 3.8303x; 3.8303x over previous
//
#include <hip/hip_runtime.h>
#include <hip/hip_bf16.h>
#include <math.h>

#define SEQ    1024
#define EMB    512
#define HID    512
#define G4     2048   // 4*HID
#define NBLK   32     // persistent scan blocks
#define UPB    16     // hidden units per scan block
#define NSLOT  4      // rotating h slots (WAR-safe at distance 4)

typedef unsigned long long u64;

// ---------------------------------------------------------------------------
// Phase A: x_gates[t][r] = dot(emb[tok[t]], w_ih[r]) + b_ih[r] + b_hh[r]
// 64x64 tile, K-chunks of 64, 4x4 micro-tile per thread.
// ---------------------------------------------------------------------------
__global__ __launch_bounds__(256) void xgates_kernel(
    const int* __restrict__ tok, const float* __restrict__ emb,
    const float* __restrict__ w_ih, const float* __restrict__ b_ih,
    const float* __restrict__ b_hh, float* __restrict__ xg)
{
  __shared__ float xs[64][68];   // +4 pad breaks power-of-2 bank stride
  __shared__ float wsh[64][68];
  __shared__ int   tok_s[64];

  const int tid = threadIdx.x;
  const int r0  = (int)blockIdx.x * 64;   // gate-row tile
  const int t0  = (int)blockIdx.y * 64;   // seq tile

  if (tid < 64) tok_s[tid] = tok[t0 + tid];
  __syncthreads();

  const int tx = tid & 15;   // r micro
  const int ty = tid >> 4;   // t micro

  float acc[4][4];
#pragma unroll
  for (int i = 0; i < 4; ++i)
#pragma unroll
    for (int j = 0; j < 4; ++j) acc[i][j] = 0.f;

  for (int kc = 0; kc < EMB; kc += 64) {
#pragma unroll
    for (int it = 0; it < 4; ++it) {
      int id  = it * 256 + tid;    // 0..1023 float4 slots
      int row = id >> 4;           // 0..63
      int c4  = id & 15;           // 0..15
      float4 xv = *(const float4*)(emb + (size_t)tok_s[row] * EMB + kc + c4 * 4);
      *(float4*)&xs[row][c4 * 4] = xv;
      float4 wv = *(const float4*)(w_ih + (size_t)(r0 + row) * EMB + kc + c4 * 4);
      *(float4*)&wsh[row][c4 * 4] = wv;
    }
    __syncthreads();

#pragma unroll
    for (int k4 = 0; k4 < 16; ++k4) {
      float4 xv[4], wv[4];
#pragma unroll
      for (int i = 0; i < 4; ++i) xv[i] = *(const float4*)&xs[ty * 4 + i][k4 * 4];
#pragma unroll
      for (int j = 0; j < 4; ++j) wv[j] = *(const float4*)&wsh[tx * 4 + j][k4 * 4];
#pragma unroll
      for (int i = 0; i < 4; ++i)
#pragma unroll
        for (int j = 0; j < 4; ++j) {
          acc[i][j] += xv[i].x * wv[j].x + xv[i].y * wv[j].y
                     + xv[i].z * wv[j].z + xv[i].w * wv[j].w;
        }
    }
    __syncthreads();
  }

  const int rbase = r0 + tx * 4;
  float bias[4];
#pragma unroll
  for (int j = 0; j < 4; ++j) bias[j] = b_ih[rbase + j] + b_hh[rbase + j];

#pragma unroll
  for (int i = 0; i < 4; ++i) {
    int t = t0 + ty * 4 + i;
    float4 o;
    o.x = acc[i][0] + bias[0];
    o.y = acc[i][1] + bias[1];
    o.z = acc[i][2] + bias[2];
    o.w = acc[i][3] + bias[3];
    *(float4*)(xg + (size_t)t * G4 + rbase) = o;
  }
}

// ---------------------------------------------------------------------------
// Phase B: sequential LSTM scan, 32 persistent blocks x 512 threads.
// Self-synchronizing h exchange: each h element is a u64 (tag<<32)|f32bits
// stored with one relaxed agent-scope atomic into a 4-slot rotating buffer.
// No flags, no fences, ONE __syncthreads per step.
//   wave w (0..7) = k-segment [64w, 64w+64); lane l (0..63) = local gate row.
//   Each wave polls/stages its own h segment (lockstep -> no barrier).
// ---------------------------------------------------------------------------
__global__ __launch_bounds__(512) void lstm_scan_kernel(
    const float* __restrict__ xg, const float* __restrict__ w_hh,
    u64* hslot /* [NSLOT][HID] */)
{
  __shared__ float h_lds[512];          // per-wave disjoint 64-float regions
  __shared__ float part_lds[2][8 * 64]; // double-buffered partials

  const int tid = threadIdx.x;
  const int blk = blockIdx.x;
  const int w   = tid >> 6;            // wave id = k-segment
  const int l   = tid & 63;            // lane   = local gate row
  const int q   = l >> 4;              // gate type (i,f,g,o)
  const int jj  = l & 15;              // local hidden unit
  const int grow = q * HID + blk * UPB + jj;  // global gate row

  // This thread's 64 w_hh weights -> VGPRs.
  float wreg[64];
  {
    const float* wp = w_hh + (size_t)grow * HID + w * 64;
#pragma unroll
    for (int k4 = 0; k4 < 16; ++k4) {
      float4 v = ((const float4*)wp)[k4];
      wreg[4 * k4 + 0] = v.x; wreg[4 * k4 + 1] = v.y;
      wreg[4 * k4 + 2] = v.z; wreg[4 * k4 + 3] = v.w;
    }
  }

  float c_reg = 0.f;                       // cell state (wave0 lanes 0..15)
  float xgv = (w == 0) ? xg[grow] : 0.f;   // x_gates[0][grow]

  for (int t = 0; t < SEQ; ++t) {
    // Poll own h element: tag must equal t. Tag+payload in one atomic word.
    u64 word;
    const u64* src = hslot + (size_t)(t & (NSLOT - 1)) * HID + tid;
    do {
      word = __hip_atomic_load(src, __ATOMIC_RELAXED, __HIP_MEMORY_SCOPE_AGENT);
    } while ((unsigned)(word >> 32) != (unsigned)t);
    h_lds[tid] = __uint_as_float((unsigned)(word & 0xffffffffu));
    // No barrier: wave w reads only h_lds[64w..64w+63], written by its own
    // lanes (lockstep within a wave; lgkmcnt orders the ds ops).

    const float* hb = &h_lds[w * 64];
    float p0 = 0.f, p1 = 0.f, p2 = 0.f, p3 = 0.f;
#pragma unroll
    for (int k = 0; k < 16; ++k) {
      p0 += wreg[k]      * hb[k];
      p1 += wreg[k + 16] * hb[k + 16];
      p2 += wreg[k + 32] * hb[k + 32];
      p3 += wreg[k + 48] * hb[k + 48];
    }
    part_lds[t & 1][w * 64 + l] = (p0 + p1) + (p2 + p3);
    __syncthreads();   // the only barrier per step

    if (w == 0) {
      const float* pp = &part_lds[t & 1][0];
      float s = ((pp[l]       + pp[64 + l]) + (pp[128 + l] + pp[192 + l]))
              + ((pp[256 + l] + pp[320 + l]) + (pp[384 + l] + pp[448 + l]));
      float gv = s + xgv;

      // prefetch next step's xg (used next iteration -> latency hidden)
      int tn = (t + 1 < SEQ) ? (t + 1) : (SEQ - 1);
      xgv = xg[(size_t)tn * G4 + grow];

      // gather the 4 gate values for unit jj into lanes 0..15
      float gi = __shfl(gv, jj,      64);
      float gf = __shfl(gv, jj + 16, 64);
      float gg = __shfl(gv, jj + 32, 64);
      float go = __shfl(gv, jj + 48, 64);

      if (l < UPB) {
        const float LOG2E = 1.442695041f;
        float i_ = 1.f / (1.f + __builtin_exp2f(-LOG2E * gi));
        float f_ = 1.f / (1.f + __builtin_exp2f(-LOG2E * gf));
        float g_ = 2.f / (1.f + __builtin_exp2f(-2.f * LOG2E * gg)) - 1.f;
        float o_ = 1.f / (1.f + __builtin_exp2f(-LOG2E * go));
        c_reg = f_ * c_reg + i_ * g_;
        float hv = o_ * (2.f / (1.f + __builtin_exp2f(-2.f * LOG2E * c_reg)) - 1.f);
        u64 outw = ((u64)(unsigned)(t + 1) << 32) | (u64)__float_as_uint(hv);
        __hip_atomic_store(hslot + (size_t)((t + 1) & (NSLOT - 1)) * HID + blk * UPB + jj,
                           outw, __ATOMIC_RELAXED, __HIP_MEMORY_SCOPE_AGENT);
      }
    }
  }
}

// ---------------------------------------------------------------------------
// Phase C: attn = sigmoid(h @ attn_w^T + attn_b) broadcast to (64,32,32);
// also emit x_instr_rep = h. h comes packed in hslot slot 0 (tag 1024).
// ---------------------------------------------------------------------------
__global__ __launch_bounds__(256) void head_kernel(
    const u64* __restrict__ hpacked, const float* __restrict__ attn_w,
    const float* __restrict__ attn_b, float* __restrict__ out)
{
  __shared__ float red[4];
  __shared__ float aval;
  const int r   = blockIdx.x;   // 0..63
  const int tid = threadIdx.x;

  float h0 = __uint_as_float((unsigned)(hpacked[tid]       & 0xffffffffu));
  float h1 = __uint_as_float((unsigned)(hpacked[256 + tid] & 0xffffffffu));

  float p = attn_w[(size_t)r * HID + tid] * h0
          + attn_w[(size_t)r * HID + 256 + tid] * h1;
#pragma unroll
  for (int off = 1; off < 64; off <<= 1) p += __shfl_xor(p, off, 64);
  if ((tid & 63) == 0) red[tid >> 6] = p;
  __syncthreads();
  if (tid == 0) {
    float sum = red[0] + red[1] + red[2] + red[3] + attn_b[r];
    aval = 1.f / (1.f + __expf(-sum));
  }
  __syncthreads();

  float a = aval;
  float4 av = make_float4(a, a, a, a);
  ((float4*)(out + (size_t)r * 1024))[tid] = av;   // 256*16B = 1024 floats

  if (r == 0) {   // x_instr_rep = h (512 floats) at offset 64*32*32
    out[65536 + tid]       = h0;
    out[65536 + 256 + tid] = h1;
  }
}

// ---------------------------------------------------------------------------
extern "C" void kernel_launch(void* const* d_in, const int* in_sizes, int n_in,
                              void* d_out, int out_size, void* d_ws, size_t ws_size,
                              hipStream_t stream) {
  const int*   tok    = (const int*)  d_in[0];
  const float* emb    = (const float*)d_in[1];
  const float* w_ih   = (const float*)d_in[2];
  const float* w_hh   = (const float*)d_in[3];
  const float* b_ih   = (const float*)d_in[4];
  const float* b_hh   = (const float*)d_in[5];
  const float* attn_w = (const float*)d_in[6];
  const float* attn_b = (const float*)d_in[7];
  float* out = (float*)d_out;

  char* ws = (char*)d_ws;
  float* xg    = (float*)ws;                              // 8 MB
  u64*   hslot = (u64*)(ws + (size_t)SEQ * G4 * 4);       // 4*512*8 = 16 KB

  // ws is poisoned 0xAA before every launch: zero the h slots (tag 0 == h^0=0).
  hipMemsetAsync(hslot, 0, NSLOT * HID * sizeof(u64), stream);

  dim3 gA(G4 / 64, SEQ / 64);   // 32 x 16 tiles
  xgates_kernel<<<gA, 256, 0, stream>>>(tok, emb, w_ih, b_ih, b_hh, xg);
  lstm_scan_kernel<<<NBLK, 512, 0, stream>>>(xg, w_hh, hslot);
  // h^1024 lands in slot (1024 & 3) == 0.
  head_kernel<<<64, 256, 0, stream>>>(hslot, attn_w, attn_b, out);
}